// Round 1
// baseline (683.558 us; speedup 1.0000x reference)
//
#include <hip/hip_runtime.h>
#include <math.h>

// Problem constants
#define BB 2
#define TT 2048
#define DD 1024
#define HH 16
#define DH 64
#define BT (BB*TT)          // 4096
#define CC 64               // chunk length
#define NC (TT/CC)          // 32 chunks
#define EPSV 1e-6f

// ---------------------------------------------------------------------------
// GEMM: C[m][n] = act( sum_k A[m][k] * W[n][k] + bias[n] )
// A: M x K row-major, W: N x K row-major (i.e. B^T gemm), M,N mult of 64, K mult of 16
// act=1 -> elu(x)+1 feature map
// ---------------------------------------------------------------------------
__global__ __launch_bounds__(256) void gemm_bt_f32(
    const float* __restrict__ A, const float* __restrict__ W,
    const float* __restrict__ bias, float* __restrict__ C,
    int M, int N, int K, int act)
{
    __shared__ __align__(16) float As[16][68];
    __shared__ __align__(16) float Bs[16][68];
    int tid = threadIdx.x;
    int m0 = blockIdx.y * 64, n0 = blockIdx.x * 64;
    int lr = tid >> 2;            // 0..63 row of tile being loaded
    int lc = (tid & 3) * 4;       // k-col group 0,4,8,12
    int tx = tid & 15, ty = tid >> 4;
    float acc[4][4] = {};
    const float* Ap = A + (size_t)(m0 + lr) * K + lc;
    const float* Wp = W + (size_t)(n0 + lr) * K + lc;
    for (int kt = 0; kt < K; kt += 16) {
        float4 a4 = *(const float4*)(Ap + kt);
        float4 b4 = *(const float4*)(Wp + kt);
        As[lc + 0][lr] = a4.x; As[lc + 1][lr] = a4.y;
        As[lc + 2][lr] = a4.z; As[lc + 3][lr] = a4.w;
        Bs[lc + 0][lr] = b4.x; Bs[lc + 1][lr] = b4.y;
        Bs[lc + 2][lr] = b4.z; Bs[lc + 3][lr] = b4.w;
        __syncthreads();
#pragma unroll
        for (int kk = 0; kk < 16; kk++) {
            float4 av = *(const float4*)&As[kk][ty * 4];
            float4 bv = *(const float4*)&Bs[kk][tx * 4];
            float aa[4] = {av.x, av.y, av.z, av.w};
            float bb[4] = {bv.x, bv.y, bv.z, bv.w};
#pragma unroll
            for (int i = 0; i < 4; i++)
#pragma unroll
                for (int j = 0; j < 4; j++) acc[i][j] += aa[i] * bb[j];
        }
        __syncthreads();
    }
    float4 bi4 = *(const float4*)&bias[n0 + tx * 4];
    float bb[4] = {bi4.x, bi4.y, bi4.z, bi4.w};
#pragma unroll
    for (int i = 0; i < 4; i++) {
        float vals[4];
#pragma unroll
        for (int j = 0; j < 4; j++) {
            float x = acc[i][j] + bb[j];
            if (act) x = (x > 0.f) ? (x + 1.f) : expf(x);  // elu(x)+1
            vals[j] = x;
        }
        *(float4*)&C[(size_t)(m0 + ty * 4 + i) * N + n0 + tx * 4] =
            make_float4(vals[0], vals[1], vals[2], vals[3]);
    }
}

// ---------------------------------------------------------------------------
// Per-chunk KV sums: S_c[d][e] = sum_{t in chunk} k[t][d]*v[t][e]; z_c[d]=sum k[t][d]
// grid = B*H*NC blocks. k,v layout: (b*T+t)*D + h*64 + dh
// ---------------------------------------------------------------------------
__global__ __launch_bounds__(256) void chunk_kv_f32(
    const float* __restrict__ k, const float* __restrict__ v,
    float* __restrict__ S, float* __restrict__ z)
{
    int blk = blockIdx.x;
    int c = blk & (NC - 1);
    int bh = blk >> 5;               // NC=32
    int b = bh >> 4, h = bh & 15;
    __shared__ __align__(16) float Ks[64][68];
    __shared__ __align__(16) float Vs[64][68];
    int tid = threadIdx.x;
    int rrow = tid >> 4;
    int rc4 = (tid & 15) * 4;
#pragma unroll
    for (int r = 0; r < 4; r++) {
        int row = rrow + r * 16;
        int g = (b * TT + c * CC + row) * DD + h * DH + rc4;
        *(float4*)&Ks[row][rc4] = *(const float4*)&k[g];
        *(float4*)&Vs[row][rc4] = *(const float4*)&v[g];
    }
    __syncthreads();
    int d0 = (tid >> 4) * 4, e0 = (tid & 15) * 4;
    float acc[4][4] = {};
    for (int t = 0; t < CC; t++) {
        float4 a4 = *(const float4*)&Ks[t][d0];
        float4 b4 = *(const float4*)&Vs[t][e0];
        float aa[4] = {a4.x, a4.y, a4.z, a4.w};
        float bb[4] = {b4.x, b4.y, b4.z, b4.w};
#pragma unroll
        for (int i = 0; i < 4; i++)
#pragma unroll
            for (int j = 0; j < 4; j++) acc[i][j] += aa[i] * bb[j];
    }
    size_t sbase = (size_t)blk * 4096;
#pragma unroll
    for (int i = 0; i < 4; i++)
        *(float4*)&S[sbase + (d0 + i) * 64 + e0] =
            make_float4(acc[i][0], acc[i][1], acc[i][2], acc[i][3]);
    if (tid < 64) {
        float s = 0.f;
        for (int t = 0; t < CC; t++) s += Ks[t][tid];
        z[(size_t)blk * 64 + tid] = s;
    }
}

// ---------------------------------------------------------------------------
// In-place exclusive prefix over chunks. grid = B*H blocks.
// ---------------------------------------------------------------------------
__global__ __launch_bounds__(256) void prefix_f32(float* __restrict__ S, float* __restrict__ z)
{
    int bh = blockIdx.x;
    int tid = threadIdx.x;
    size_t base = (size_t)bh * NC * 4096;
    float run[16];
#pragma unroll
    for (int r = 0; r < 16; r++) run[r] = 0.f;
    for (int c = 0; c < NC; c++) {
#pragma unroll
        for (int r = 0; r < 16; r++) {
            size_t idx = base + (size_t)c * 4096 + r * 256 + tid;
            float t = S[idx];
            S[idx] = run[r];
            run[r] += t;
        }
    }
    if (tid < 64) {
        float rz = 0.f;
        size_t zb = (size_t)bh * NC * 64;
        for (int c = 0; c < NC; c++) {
            float t = z[zb + c * 64 + tid];
            z[zb + c * 64 + tid] = rz;
            rz += t;
        }
    }
}

// ---------------------------------------------------------------------------
// Fused chunk attention. grid = B*H*NC blocks, 256 threads.
// out[t][e] = ( q_t . Sp[.][e]  +  sum_{s<=t} (q_t.k_s) v_s[e] ) / max(q_t.(zp+cumsum k), eps)
// ---------------------------------------------------------------------------
__global__ __launch_bounds__(256) void attn_chunk_f32(
    const float* __restrict__ q, const float* __restrict__ k,
    const float* __restrict__ v, const float* __restrict__ Sx,
    const float* __restrict__ zx, float* __restrict__ out)
{
    // shared layout (floats):
    //   QT  [64][65]  q transposed: QT[d*65 + t]              @ 0      (4160)
    //   KS  [64][65]  k rows: KS[t*65 + d]; later ALT[s*64+t] @ 4160   (4160)
    //   SP  [64][64]  S_prefix rows d; later VS[s*64+e]       @ 8320   (4096)
    //   DP  [64][16]  masked row partial sums of A            @ 12416  (1024)
    //   ZP  [64]                                              @ 13440
    //   DI  [64]      1/den                                   @ 13504
    __shared__ __align__(16) float sm[13568];
    float* QT = sm;
    float* KS = sm + 4160;
    float* SP = sm + 8320;
    float* DP = sm + 12416;
    float* ZP = sm + 13440;
    float* DI = sm + 13504;

    int tid = threadIdx.x;
    int blk = blockIdx.x;
    int c = blk & (NC - 1);
    int bh = blk >> 5;
    int b = bh >> 4, h = bh & 15;

    int rrow = tid >> 4;
    int rc4 = (tid & 15) * 4;

    // phase 1: load Q (transposed, scalar scatter), K rows, zp
#pragma unroll
    for (int r = 0; r < 4; r++) {
        int row = rrow + r * 16;
        int g = (b * TT + c * CC + row) * DD + h * DH + rc4;
        float4 q4 = *(const float4*)&q[g];
        QT[(rc4 + 0) * 65 + row] = q4.x;
        QT[(rc4 + 1) * 65 + row] = q4.y;
        QT[(rc4 + 2) * 65 + row] = q4.z;
        QT[(rc4 + 3) * 65 + row] = q4.w;
        float4 k4 = *(const float4*)&k[g];
        KS[row * 65 + rc4 + 0] = k4.x;
        KS[row * 65 + rc4 + 1] = k4.y;
        KS[row * 65 + rc4 + 2] = k4.z;
        KS[row * 65 + rc4 + 3] = k4.w;
    }
    if (tid < 64) ZP[tid] = zx[(size_t)blk * 64 + tid];
    __syncthreads();

    // phase 2: A[t][s] = q_t . k_s   (4x4 per thread, kept in registers)
    int t0 = (tid >> 4) * 4, s0 = (tid & 15) * 4;
    float acc[4][4] = {};
    for (int d = 0; d < 64; d++) {
        float qa[4], kb[4];
#pragma unroll
        for (int i = 0; i < 4; i++) qa[i] = QT[d * 65 + t0 + i];
#pragma unroll
        for (int j = 0; j < 4; j++) kb[j] = KS[(s0 + j) * 65 + d];
#pragma unroll
        for (int i = 0; i < 4; i++)
#pragma unroll
            for (int j = 0; j < 4; j++) acc[i][j] += qa[i] * kb[j];
    }
#pragma unroll
    for (int i = 0; i < 4; i++) {
        float rs = 0.f;
#pragma unroll
        for (int j = 0; j < 4; j++)
            if (s0 + j <= t0 + i) rs += acc[i][j];
        DP[(t0 + i) * 16 + (tid & 15)] = rs;
    }
    __syncthreads();

    // phase 3: load S_prefix; threads<64 compute 1/den
#pragma unroll
    for (int r = 0; r < 4; r++) {
        int row = rrow + r * 16;
        *(float4*)&SP[row * 64 + rc4] =
            *(const float4*)&Sx[(size_t)blk * 4096 + row * 64 + rc4];
    }
    if (tid < 64) {
        int t = tid;
        float s = 0.f;
        for (int d = 0; d < 64; d++) s += QT[d * 65 + t] * ZP[d];
#pragma unroll
        for (int p = 0; p < 16; p++) s += DP[t * 16 + p];
        DI[t] = 1.f / fmaxf(s, EPSV);
    }
    __syncthreads();

    // phase 4: inter-chunk part  o[e] = sum_d q_t[d] * Sp[d][e]
    int t = tid >> 2;
    int e0 = (tid & 3) * 16;
    float o[16] = {};
    for (int d = 0; d < 64; d++) {
        float qv = QT[d * 65 + t];
#pragma unroll
        for (int jj = 0; jj < 4; jj++) {
            float4 s4 = *(const float4*)&SP[d * 64 + e0 + jj * 4];
            o[jj * 4 + 0] += qv * s4.x;
            o[jj * 4 + 1] += qv * s4.y;
            o[jj * 4 + 2] += qv * s4.z;
            o[jj * 4 + 3] += qv * s4.w;
        }
    }
    __syncthreads();

    // phase 5: overlay — A into KS region (transposed), V into SP region
    float* ALT = KS;  // ALT[s*64 + t]
    float* VS = SP;   // VS[s*64 + e]
#pragma unroll
    for (int i = 0; i < 4; i++)
#pragma unroll
        for (int j = 0; j < 4; j++)
            ALT[(s0 + j) * 64 + (t0 + i)] = acc[i][j];
#pragma unroll
    for (int r = 0; r < 4; r++) {
        int row = rrow + r * 16;
        int g = (b * TT + c * CC + row) * DD + h * DH + rc4;
        *(float4*)&VS[row * 64 + rc4] = *(const float4*)&v[g];
    }
    __syncthreads();

    // phase 6: intra-chunk causal part + divide + store
    for (int s = 0; s <= t; s++) {
        float av = ALT[s * 64 + t];
#pragma unroll
        for (int jj = 0; jj < 4; jj++) {
            float4 v4 = *(const float4*)&VS[s * 64 + e0 + jj * 4];
            o[jj * 4 + 0] += av * v4.x;
            o[jj * 4 + 1] += av * v4.y;
            o[jj * 4 + 2] += av * v4.z;
            o[jj * 4 + 3] += av * v4.w;
        }
    }
    float di = DI[t];
    int g = (b * TT + c * CC + t) * DD + h * DH + e0;
#pragma unroll
    for (int jj = 0; jj < 4; jj++)
        *(float4*)&out[g + jj * 4] = make_float4(
            o[jj * 4 + 0] * di, o[jj * 4 + 1] * di,
            o[jj * 4 + 2] * di, o[jj * 4 + 3] * di);
}

// ---------------------------------------------------------------------------
extern "C" void kernel_launch(void* const* d_in, const int* in_sizes, int n_in,
                              void* d_out, int out_size, void* d_ws, size_t ws_size,
                              hipStream_t stream) {
    const float* x  = (const float*)d_in[0];
    const float* Wq = (const float*)d_in[1];
    const float* bq = (const float*)d_in[2];
    const float* Wk = (const float*)d_in[3];
    const float* bk = (const float*)d_in[4];
    const float* Wv = (const float*)d_in[5];
    const float* bv = (const float*)d_in[6];
    const float* Wo = (const float*)d_in[7];
    const float* bo = (const float*)d_in[8];
    float* out = (float*)d_out;

    float* ws = (float*)d_ws;
    float* q    = ws;                       // 4096*1024
    float* kbuf = ws + 4194304;
    float* vbuf = ws + 8388608;
    float* attn = ws + 12582912;
    float* S    = ws + 16777216;            // B*H*NC*64*64 = 4194304
    float* z    = ws + 20971520;            // B*H*NC*64    = 65536

    dim3 gg(DD / 64, BT / 64);              // (16, 64)
    gemm_bt_f32<<<gg, 256, 0, stream>>>(x, Wq, bq, q,    BT, DD, DD, 1);
    gemm_bt_f32<<<gg, 256, 0, stream>>>(x, Wk, bk, kbuf, BT, DD, DD, 1);
    gemm_bt_f32<<<gg, 256, 0, stream>>>(x, Wv, bv, vbuf, BT, DD, DD, 0);
    chunk_kv_f32<<<BB * HH * NC, 256, 0, stream>>>(kbuf, vbuf, S, z);
    prefix_f32<<<BB * HH, 256, 0, stream>>>(S, z);
    attn_chunk_f32<<<BB * HH * NC, 256, 0, stream>>>(q, kbuf, vbuf, S, z, attn);
    gemm_bt_f32<<<gg, 256, 0, stream>>>(attn, Wo, bo, out, BT, DD, DD, 0);
}

// Round 2
// 237.700 us; speedup vs baseline: 2.8757x; 2.8757x over previous
//
#include <hip/hip_runtime.h>
#include <math.h>

// Problem constants
#define BB 2
#define TT 2048
#define DD 1024
#define HH 16
#define DH 64
#define BT (BB*TT)          // 4096
#define CC 64               // chunk length
#define NC (TT/CC)          // 32 chunks
#define EPSV 1e-6f
#define QS 3072             // fused qkv row stride

typedef __attribute__((ext_vector_type(8))) short short8;
typedef __attribute__((ext_vector_type(4))) float f32x4;

__device__ inline ushort f2bf(float f) {
    unsigned u = __float_as_uint(f);
    u = (u + 0x7fffu + ((u >> 16) & 1u)) >> 16;   // RNE
    return (ushort)u;
}

__device__ inline void async16(const void* g, void* l) {
    __builtin_amdgcn_global_load_lds(
        (const __attribute__((address_space(1))) void*)g,
        (__attribute__((address_space(3))) void*)l, 16, 0, 0);
}

// ---------------------------------------------------------------------------
// Pack fp32 -> bf16: xb (4M), Wqkvb = [Wq;Wk;Wv] (3M), Wob (1M); biasq fp32.
// ---------------------------------------------------------------------------
__global__ __launch_bounds__(256) void convert_pack(
    const float* __restrict__ x, const float* __restrict__ Wq,
    const float* __restrict__ Wk, const float* __restrict__ Wv,
    const float* __restrict__ Wo, const float* __restrict__ bq,
    const float* __restrict__ bk, const float* __restrict__ bv,
    ushort* __restrict__ xb, ushort* __restrict__ Wqkvb,
    ushort* __restrict__ Wob, float* __restrict__ biasq)
{
    int i = blockIdx.x * 256 + threadIdx.x;      // 0..1048575
    int idx = i * 8;
    const float* src;
    ushort* dst;
    if (idx < 4194304) { src = x + idx; dst = xb + idx; }
    else if (idx < 7340032) {
        int r = idx - 4194304;
        int w = r >> 20;
        int o = r & 1048575;
        src = (w == 0 ? Wq : (w == 1 ? Wk : Wv)) + o;
        dst = Wqkvb + r;
    } else {
        int r = idx - 7340032;
        src = Wo + r; dst = Wob + r;
    }
    float4 f0 = *(const float4*)src;
    float4 f1 = *(const float4*)(src + 4);
    *(ushort4*)dst = make_ushort4(f2bf(f0.x), f2bf(f0.y), f2bf(f0.z), f2bf(f0.w));
    *(ushort4*)(dst + 4) = make_ushort4(f2bf(f1.x), f2bf(f1.y), f2bf(f1.z), f2bf(f1.w));
    if (i < 3072)
        biasq[i] = (i < 1024) ? bq[i] : (i < 2048) ? bk[i - 1024] : bv[i - 2048];
}

// ---------------------------------------------------------------------------
// MFMA bf16 GEMM: C[m][n] = act(sum_k A[m][k]*W[n][k] + bias[n])
// A: M x K bf16, W: N x K bf16 (B^T layout). BM=BN=128, BK=32, 256 thr/4 waves.
// act: elu(x)+1 iff col < act_limit.
// global_load_lds 16B staging, XOR k-group swizzle (conflict-free ds_read_b128).
// ---------------------------------------------------------------------------
#define BM 128
#define BN 128
#define BK 32

__global__ __launch_bounds__(256) void gemm_mfma(
    const ushort* __restrict__ A, const ushort* __restrict__ W,
    const float* __restrict__ bias, float* __restrict__ C,
    int M, int N, int K, int act_limit)
{
    __shared__ __align__(16) ushort As[BM * BK];
    __shared__ __align__(16) ushort Bs[BN * BK];
    int tid = threadIdx.x;
    int lane = tid & 63, wave = tid >> 6;
    int m0 = blockIdx.y * BM, n0 = blockIdx.x * BN;
    int wm = (wave >> 1) * 64, wn = (wave & 1) * 64;

    // staging: slot s = wave*2 + r covers LDS bytes [s*1024, s*1024+1024)
    // lane l -> row = s*16 + l/4, position p = l&3; data k-group = p ^ (row&3)
    int p = lane & 3;
    int r0 = (wave * 2 + 0) * 16 + (lane >> 2);
    int r1 = (wave * 2 + 1) * 16 + (lane >> 2);
    int kg0 = p ^ (r0 & 3);
    int kg1 = p ^ (r1 & 3);
    const ushort* gA0 = A + (size_t)(m0 + r0) * K + kg0 * 8;
    const ushort* gA1 = A + (size_t)(m0 + r1) * K + kg1 * 8;
    const ushort* gB0 = W + (size_t)(n0 + r0) * K + kg0 * 8;
    const ushort* gB1 = W + (size_t)(n0 + r1) * K + kg1 * 8;
    ushort* lA0 = &As[r0 * BK + p * 8];
    ushort* lA1 = &As[r1 * BK + p * 8];
    ushort* lB0 = &Bs[r0 * BK + p * 8];
    ushort* lB1 = &Bs[r1 * BK + p * 8];

    // fragment read addresses: A[m=lane&15][k=(lane>>4)*8+j], swizzled position
    int fr = lane & 15;
    int g = lane >> 4;
    int pk = (g ^ (fr & 3)) * 8;
    const ushort* aBase = &As[(wm + fr) * BK + pk];
    const ushort* bBase = &Bs[(wn + fr) * BK + pk];

    f32x4 acc[4][4];
#pragma unroll
    for (int i = 0; i < 4; i++)
#pragma unroll
        for (int j = 0; j < 4; j++) acc[i][j] = (f32x4){0.f, 0.f, 0.f, 0.f};

    for (int kt = 0; kt < K; kt += BK) {
        async16(gA0 + kt, lA0);
        async16(gA1 + kt, lA1);
        async16(gB0 + kt, lB0);
        async16(gB1 + kt, lB1);
        __syncthreads();   // drains vmcnt: async LDS writes visible
        short8 af[4], bf[4];
#pragma unroll
        for (int i = 0; i < 4; i++) af[i] = *(const short8*)(aBase + i * 16 * BK);
#pragma unroll
        for (int j = 0; j < 4; j++) bf[j] = *(const short8*)(bBase + j * 16 * BK);
#pragma unroll
        for (int i = 0; i < 4; i++)
#pragma unroll
            for (int j = 0; j < 4; j++)
                acc[i][j] = __builtin_amdgcn_mfma_f32_16x16x32_bf16(
                    af[i], bf[j], acc[i][j], 0, 0, 0);
        __syncthreads();   // all reads done before next staging overwrites
    }

    // epilogue: C/D layout col=lane&15, row=(lane>>4)*4+reg
#pragma unroll
    for (int j = 0; j < 4; j++) {
        int col = n0 + wn + j * 16 + fr;
        float bv_ = bias[col];
        bool act = col < act_limit;
#pragma unroll
        for (int i = 0; i < 4; i++) {
            int rowb = m0 + wm + i * 16 + g * 4;
#pragma unroll
            for (int r = 0; r < 4; r++) {
                float v = acc[i][j][r] + bv_;
                if (act) v = (v > 0.f) ? (v + 1.f) : expf(v);  // elu(x)+1
                C[(size_t)(rowb + r) * N + col] = v;
            }
        }
    }
}

// ---------------------------------------------------------------------------
// Per-chunk KV sums over fused qkv (stride QS).
// ---------------------------------------------------------------------------
__global__ __launch_bounds__(256) void chunk_kv_f32(
    const float* __restrict__ k, const float* __restrict__ v,
    float* __restrict__ S, float* __restrict__ z)
{
    int blk = blockIdx.x;
    int c = blk & (NC - 1);
    int bh = blk >> 5;
    int b = bh >> 4, h = bh & 15;
    __shared__ __align__(16) float Ks[64][68];
    __shared__ __align__(16) float Vs[64][68];
    int tid = threadIdx.x;
    int rrow = tid >> 4;
    int rc4 = (tid & 15) * 4;
#pragma unroll
    for (int r = 0; r < 4; r++) {
        int row = rrow + r * 16;
        int g = (b * TT + c * CC + row) * QS + h * DH + rc4;
        *(float4*)&Ks[row][rc4] = *(const float4*)&k[g];
        *(float4*)&Vs[row][rc4] = *(const float4*)&v[g];
    }
    __syncthreads();
    int d0 = (tid >> 4) * 4, e0 = (tid & 15) * 4;
    float acc[4][4] = {};
    for (int t = 0; t < CC; t++) {
        float4 a4 = *(const float4*)&Ks[t][d0];
        float4 b4 = *(const float4*)&Vs[t][e0];
        float aa[4] = {a4.x, a4.y, a4.z, a4.w};
        float bb[4] = {b4.x, b4.y, b4.z, b4.w};
#pragma unroll
        for (int i = 0; i < 4; i++)
#pragma unroll
            for (int j = 0; j < 4; j++) acc[i][j] += aa[i] * bb[j];
    }
    size_t sbase = (size_t)blk * 4096;
#pragma unroll
    for (int i = 0; i < 4; i++)
        *(float4*)&S[sbase + (d0 + i) * 64 + e0] =
            make_float4(acc[i][0], acc[i][1], acc[i][2], acc[i][3]);
    if (tid < 64) {
        float s = 0.f;
        for (int t = 0; t < CC; t++) s += Ks[t][tid];
        z[(size_t)blk * 64 + tid] = s;
    }
}

// ---------------------------------------------------------------------------
// In-place exclusive prefix over chunks. grid = B*H blocks.
// ---------------------------------------------------------------------------
__global__ __launch_bounds__(256) void prefix_f32(float* __restrict__ S, float* __restrict__ z)
{
    int bh = blockIdx.x;
    int tid = threadIdx.x;
    size_t base = (size_t)bh * NC * 4096;
    float run[16];
#pragma unroll
    for (int r = 0; r < 16; r++) run[r] = 0.f;
    for (int c = 0; c < NC; c++) {
#pragma unroll
        for (int r = 0; r < 16; r++) {
            size_t idx = base + (size_t)c * 4096 + r * 256 + tid;
            float t = S[idx];
            S[idx] = run[r];
            run[r] += t;
        }
    }
    if (tid < 64) {
        float rz = 0.f;
        size_t zb = (size_t)bh * NC * 64;
        for (int c = 0; c < NC; c++) {
            float t = z[zb + c * 64 + tid];
            z[zb + c * 64 + tid] = rz;
            rz += t;
        }
    }
}

// ---------------------------------------------------------------------------
// Fused chunk attention (fp32 math), writes bf16 for the final MFMA GEMM.
// ---------------------------------------------------------------------------
__global__ __launch_bounds__(256) void attn_chunk_f32(
    const float* __restrict__ q, const float* __restrict__ k,
    const float* __restrict__ v, const float* __restrict__ Sx,
    const float* __restrict__ zx, ushort* __restrict__ ob)
{
    __shared__ __align__(16) float sm[13568];
    float* QT = sm;            // [64][65] q transposed
    float* KS = sm + 4160;     // [64][65] k rows; later ALT[s*64+t]
    float* SP = sm + 8320;     // [64][64] S_prefix; later VS[s*64+e]
    float* DP = sm + 12416;    // [64][16]
    float* ZP = sm + 13440;    // [64]
    float* DI = sm + 13504;    // [64]

    int tid = threadIdx.x;
    int blk = blockIdx.x;
    int c = blk & (NC - 1);
    int bh = blk >> 5;
    int b = bh >> 4, h = bh & 15;

    int rrow = tid >> 4;
    int rc4 = (tid & 15) * 4;

    // phase 1: load Q (transposed), K rows, zp
#pragma unroll
    for (int r = 0; r < 4; r++) {
        int row = rrow + r * 16;
        int g = (b * TT + c * CC + row) * QS + h * DH + rc4;
        float4 q4 = *(const float4*)&q[g];
        QT[(rc4 + 0) * 65 + row] = q4.x;
        QT[(rc4 + 1) * 65 + row] = q4.y;
        QT[(rc4 + 2) * 65 + row] = q4.z;
        QT[(rc4 + 3) * 65 + row] = q4.w;
        float4 k4 = *(const float4*)&k[g];
        KS[row * 65 + rc4 + 0] = k4.x;
        KS[row * 65 + rc4 + 1] = k4.y;
        KS[row * 65 + rc4 + 2] = k4.z;
        KS[row * 65 + rc4 + 3] = k4.w;
    }
    if (tid < 64) ZP[tid] = zx[(size_t)blk * 64 + tid];
    __syncthreads();

    // phase 2: A[t][s] = q_t . k_s
    int t0 = (tid >> 4) * 4, s0 = (tid & 15) * 4;
    float acc[4][4] = {};
    for (int d = 0; d < 64; d++) {
        float qa[4], kb[4];
#pragma unroll
        for (int i = 0; i < 4; i++) qa[i] = QT[d * 65 + t0 + i];
#pragma unroll
        for (int j = 0; j < 4; j++) kb[j] = KS[(s0 + j) * 65 + d];
#pragma unroll
        for (int i = 0; i < 4; i++)
#pragma unroll
            for (int j = 0; j < 4; j++) acc[i][j] += qa[i] * kb[j];
    }
#pragma unroll
    for (int i = 0; i < 4; i++) {
        float rs = 0.f;
#pragma unroll
        for (int j = 0; j < 4; j++)
            if (s0 + j <= t0 + i) rs += acc[i][j];
        DP[(t0 + i) * 16 + (tid & 15)] = rs;
    }
    __syncthreads();

    // phase 3: load S_prefix; threads<64 compute 1/den
#pragma unroll
    for (int r = 0; r < 4; r++) {
        int row = rrow + r * 16;
        *(float4*)&SP[row * 64 + rc4] =
            *(const float4*)&Sx[(size_t)blk * 4096 + row * 64 + rc4];
    }
    if (tid < 64) {
        int t = tid;
        float s = 0.f;
        for (int d = 0; d < 64; d++) s += QT[d * 65 + t] * ZP[d];
#pragma unroll
        for (int p = 0; p < 16; p++) s += DP[t * 16 + p];
        DI[t] = 1.f / fmaxf(s, EPSV);
    }
    __syncthreads();

    // phase 4: inter-chunk o[e] = sum_d q_t[d] * Sp[d][e]
    int t = tid >> 2;
    int e0 = (tid & 3) * 16;
    float o[16] = {};
    for (int d = 0; d < 64; d++) {
        float qv = QT[d * 65 + t];
#pragma unroll
        for (int jj = 0; jj < 4; jj++) {
            float4 s4 = *(const float4*)&SP[d * 64 + e0 + jj * 4];
            o[jj * 4 + 0] += qv * s4.x;
            o[jj * 4 + 1] += qv * s4.y;
            o[jj * 4 + 2] += qv * s4.z;
            o[jj * 4 + 3] += qv * s4.w;
        }
    }
    __syncthreads();

    // phase 5: overlay A -> KS (transposed), V -> SP
    float* ALT = KS;
    float* VS = SP;
#pragma unroll
    for (int i = 0; i < 4; i++)
#pragma unroll
        for (int j = 0; j < 4; j++)
            ALT[(s0 + j) * 64 + (t0 + i)] = acc[i][j];
#pragma unroll
    for (int r = 0; r < 4; r++) {
        int row = rrow + r * 16;
        int g = (b * TT + c * CC + row) * QS + h * DH + rc4;
        *(float4*)&VS[row * 64 + rc4] = *(const float4*)&v[g];
    }
    __syncthreads();

    // phase 6: intra-chunk causal + divide + bf16 store
    for (int s = 0; s <= t; s++) {
        float av = ALT[s * 64 + t];
#pragma unroll
        for (int jj = 0; jj < 4; jj++) {
            float4 v4 = *(const float4*)&VS[s * 64 + e0 + jj * 4];
            o[jj * 4 + 0] += av * v4.x;
            o[jj * 4 + 1] += av * v4.y;
            o[jj * 4 + 2] += av * v4.z;
            o[jj * 4 + 3] += av * v4.w;
        }
    }
    float di = DI[t];
    int gidx = (b * TT + c * CC + t) * DD + h * DH + e0;
#pragma unroll
    for (int jj = 0; jj < 4; jj++) {
        *(ushort4*)&ob[gidx + jj * 4] = make_ushort4(
            f2bf(o[jj * 4 + 0] * di), f2bf(o[jj * 4 + 1] * di),
            f2bf(o[jj * 4 + 2] * di), f2bf(o[jj * 4 + 3] * di));
    }
}

// ---------------------------------------------------------------------------
extern "C" void kernel_launch(void* const* d_in, const int* in_sizes, int n_in,
                              void* d_out, int out_size, void* d_ws, size_t ws_size,
                              hipStream_t stream) {
    const float* x  = (const float*)d_in[0];
    const float* Wq = (const float*)d_in[1];
    const float* bq = (const float*)d_in[2];
    const float* Wk = (const float*)d_in[3];
    const float* bk = (const float*)d_in[4];
    const float* Wv = (const float*)d_in[5];
    const float* bv = (const float*)d_in[6];
    const float* Wo = (const float*)d_in[7];
    const float* bo = (const float*)d_in[8];
    float* out = (float*)d_out;

    char* ws = (char*)d_ws;
    ushort* xb    = (ushort*)(ws + 0);          //  8388608 B (4096x1024 bf16)
    ushort* Wqkvb = (ushort*)(ws + 8388608);    //  6291456 B (3072x1024 bf16)
    ushort* Wob   = (ushort*)(ws + 14680064);   //  2097152 B
    float*  biasq = (float*)(ws + 16777216);    //    12288 B
    float*  qkv   = (float*)(ws + 16789504);    // 50331648 B (4096x3072 f32)
    float*  S     = (float*)(ws + 67121152);    // 16777216 B
    float*  z     = (float*)(ws + 83898368);    //   262144 B
    ushort* attnb = (ushort*)(ws + 0);          // reuse xb region (dead after QKV gemm)

    convert_pack<<<4096, 256, 0, stream>>>(x, Wq, Wk, Wv, Wo, bq, bk, bv,
                                           xb, Wqkvb, Wob, biasq);
    // fused QKV projection: cols 0-1023=q, 1024-2047=k, 2048-3071=v
    gemm_mfma<<<dim3(3072 / BN, BT / BM), 256, 0, stream>>>(
        xb, Wqkvb, biasq, qkv, BT, 3072, DD, 2048);
    const float* qp = qkv;
    const float* kp = qkv + 1024;
    const float* vp = qkv + 2048;
    chunk_kv_f32<<<BB * HH * NC, 256, 0, stream>>>(kp, vp, S, z);
    prefix_f32<<<BB * HH, 256, 0, stream>>>(S, z);
    attn_chunk_f32<<<BB * HH * NC, 256, 0, stream>>>(qp, kp, vp, S, z, attnb);
    gemm_mfma<<<dim3(DD / BN, BT / BM), 256, 0, stream>>>(
        attnb, Wob, bo, out, BT, DD, DD, 0);
}

// Round 3
// 222.285 us; speedup vs baseline: 3.0751x; 1.0694x over previous
//
#include <hip/hip_runtime.h>
#include <math.h>

// Problem constants
#define BB 2
#define TT 2048
#define DD 1024
#define HH 16
#define DH 64
#define BT (BB*TT)          // 4096
#define CC 64               // chunk length
#define NC (TT/CC)          // 32 chunks
#define EPSV 1e-6f
#define QS 3072             // fused qkv row stride (bf16)

typedef __attribute__((ext_vector_type(8))) short short8;
typedef __attribute__((ext_vector_type(4))) float f32x4;

__device__ inline ushort f2bf(float f) {
    unsigned u = __float_as_uint(f);
    u = (u + 0x7fffu + ((u >> 16) & 1u)) >> 16;   // RNE
    return (ushort)u;
}
__device__ inline float bf2f(ushort u) {
    return __uint_as_float(((unsigned)u) << 16);
}

__device__ inline void async16(const void* g, void* l) {
    __builtin_amdgcn_global_load_lds(
        (const __attribute__((address_space(1))) void*)g,
        (__attribute__((address_space(3))) void*)l, 16, 0, 0);
}

// ---------------------------------------------------------------------------
// Pack fp32 -> bf16: xb (4M), Wqkvb = [Wq;Wk;Wv] (3M), Wob (1M); biasq fp32.
// ---------------------------------------------------------------------------
__global__ __launch_bounds__(256) void convert_pack(
    const float* __restrict__ x, const float* __restrict__ Wq,
    const float* __restrict__ Wk, const float* __restrict__ Wv,
    const float* __restrict__ Wo, const float* __restrict__ bq,
    const float* __restrict__ bk, const float* __restrict__ bv,
    ushort* __restrict__ xb, ushort* __restrict__ Wqkvb,
    ushort* __restrict__ Wob, float* __restrict__ biasq)
{
    int i = blockIdx.x * 256 + threadIdx.x;      // 0..1048575
    int idx = i * 8;
    const float* src;
    ushort* dst;
    if (idx < 4194304) { src = x + idx; dst = xb + idx; }
    else if (idx < 7340032) {
        int r = idx - 4194304;
        int w = r >> 20;
        int o = r & 1048575;
        src = (w == 0 ? Wq : (w == 1 ? Wk : Wv)) + o;
        dst = Wqkvb + r;
    } else {
        int r = idx - 7340032;
        src = Wo + r; dst = Wob + r;
    }
    float4 f0 = *(const float4*)src;
    float4 f1 = *(const float4*)(src + 4);
    *(ushort4*)dst = make_ushort4(f2bf(f0.x), f2bf(f0.y), f2bf(f0.z), f2bf(f0.w));
    *(ushort4*)(dst + 4) = make_ushort4(f2bf(f1.x), f2bf(f1.y), f2bf(f1.z), f2bf(f1.w));
    if (i < 3072)
        biasq[i] = (i < 1024) ? bq[i] : (i < 2048) ? bk[i - 1024] : bv[i - 2048];
}

// ---------------------------------------------------------------------------
// MFMA bf16 GEMM: C[m][n] = act(sum_k A[m][k]*W[n][k] + bias[n])
// A: M x K bf16, W: N x K bf16 (B^T). BM=BN=128, BK=32, 4 waves.
// Swizzle: data k-group at LDS (row,pos) is pos ^ ((row>>1)&3).
//   bank(row,pos) = (row&1)*16 + pos*4 -> reader pos = g ^ ((row>>1)&3) covers
//   all 8 bank-quads 2x per 16-lane phase (2-way = free).
// OBF16: bf16 output via LDS transpose (coalesced 16B stores); else fp32 direct.
// ---------------------------------------------------------------------------
#define BM 128
#define BN 128
#define BK 32

template<bool OBF16>
__global__ __launch_bounds__(256) void gemm_mfma(
    const ushort* __restrict__ A, const ushort* __restrict__ W,
    const float* __restrict__ bias, void* __restrict__ Cv,
    int M, int N, int K, int act_limit)
{
    constexpr int SMEM_US = OBF16 ? (128 * 132) : (BM * BK + BN * BK);
    __shared__ __align__(16) ushort smem[SMEM_US];
    ushort* As = smem;
    ushort* Bs = smem + BM * BK;
    int tid = threadIdx.x;
    int lane = tid & 63, wave = tid >> 6;
    int m0 = blockIdx.y * BM, n0 = blockIdx.x * BN;
    int wm = (wave >> 1) * 64, wn = (wave & 1) * 64;

    // staging: slot s = wave*2 + r covers LDS bytes [s*1024, s*1024+1024)
    int p = lane & 3;
    int r0 = (wave * 2 + 0) * 16 + (lane >> 2);
    int r1 = (wave * 2 + 1) * 16 + (lane >> 2);
    int kg0 = p ^ ((r0 >> 1) & 3);
    int kg1 = p ^ ((r1 >> 1) & 3);
    const ushort* gA0 = A + (size_t)(m0 + r0) * K + kg0 * 8;
    const ushort* gA1 = A + (size_t)(m0 + r1) * K + kg1 * 8;
    const ushort* gB0 = W + (size_t)(n0 + r0) * K + kg0 * 8;
    const ushort* gB1 = W + (size_t)(n0 + r1) * K + kg1 * 8;
    ushort* lA0 = &As[r0 * BK + p * 8];
    ushort* lA1 = &As[r1 * BK + p * 8];
    ushort* lB0 = &Bs[r0 * BK + p * 8];
    ushort* lB1 = &Bs[r1 * BK + p * 8];

    // fragment reads: A[m=lane&15][k=(lane>>4)*8+j], swizzled position
    int fr = lane & 15;
    int g = lane >> 4;
    int pk = (g ^ ((fr >> 1) & 3)) * 8;
    const ushort* aBase = &As[(wm + fr) * BK + pk];
    const ushort* bBase = &Bs[(wn + fr) * BK + pk];

    f32x4 acc[4][4];
#pragma unroll
    for (int i = 0; i < 4; i++)
#pragma unroll
        for (int j = 0; j < 4; j++) acc[i][j] = (f32x4){0.f, 0.f, 0.f, 0.f};

    for (int kt = 0; kt < K; kt += BK) {
        async16(gA0 + kt, lA0);
        async16(gA1 + kt, lA1);
        async16(gB0 + kt, lB0);
        async16(gB1 + kt, lB1);
        __syncthreads();
        short8 af[4], bf[4];
#pragma unroll
        for (int i = 0; i < 4; i++) af[i] = *(const short8*)(aBase + i * 16 * BK);
#pragma unroll
        for (int j = 0; j < 4; j++) bf[j] = *(const short8*)(bBase + j * 16 * BK);
#pragma unroll
        for (int i = 0; i < 4; i++)
#pragma unroll
            for (int j = 0; j < 4; j++)
                acc[i][j] = __builtin_amdgcn_mfma_f32_16x16x32_bf16(
                    af[i], bf[j], acc[i][j], 0, 0, 0);
        __syncthreads();
    }

    // epilogue: C/D layout col=lane&15, row=(lane>>4)*4+reg
    if (OBF16) {
        ushort* Cs = smem;   // 128 x 132 (stride 132: bank = 2*row + col/2, 2-way)
#pragma unroll
        for (int j = 0; j < 4; j++) {
            int colL = wn + j * 16 + fr;
            float bv_ = bias[n0 + colL];
            bool act = (n0 + colL) < act_limit;
#pragma unroll
            for (int i = 0; i < 4; i++) {
                int rowL = wm + i * 16 + g * 4;
#pragma unroll
                for (int r = 0; r < 4; r++) {
                    float v = acc[i][j][r] + bv_;
                    if (act) v = (v > 0.f) ? (v + 1.f) : expf(v);
                    Cs[(rowL + r) * 132 + colL] = f2bf(v);
                }
            }
        }
        __syncthreads();
        ushort* C = (ushort*)Cv;
        int orow = tid >> 4, ocol = (tid & 15) * 8;
#pragma unroll
        for (int it = 0; it < 8; it++) {
            int rr = orow + it * 16;
            ushort4 lo = *(const ushort4*)&Cs[rr * 132 + ocol];
            ushort4 hi = *(const ushort4*)&Cs[rr * 132 + ocol + 4];
            ushort pk8[8] = {lo.x, lo.y, lo.z, lo.w, hi.x, hi.y, hi.z, hi.w};
            *(uint4*)&C[(size_t)(m0 + rr) * N + n0 + ocol] = *(uint4*)pk8;
        }
    } else {
        float* C = (float*)Cv;
#pragma unroll
        for (int j = 0; j < 4; j++) {
            int col = n0 + wn + j * 16 + fr;
            float bv_ = bias[col];
            bool act = col < act_limit;
#pragma unroll
            for (int i = 0; i < 4; i++) {
                int rowb = m0 + wm + i * 16 + g * 4;
#pragma unroll
                for (int r = 0; r < 4; r++) {
                    float v = acc[i][j][r] + bv_;
                    if (act) v = (v > 0.f) ? (v + 1.f) : expf(v);
                    C[(size_t)(rowb + r) * N + col] = v;
                }
            }
        }
    }
}

// ---------------------------------------------------------------------------
// Per-chunk KV sums over fused bf16 qkv (stride QS).
// ---------------------------------------------------------------------------
__global__ __launch_bounds__(256) void chunk_kv(
    const ushort* __restrict__ k, const ushort* __restrict__ v,
    float* __restrict__ S, float* __restrict__ z)
{
    int blk = blockIdx.x;
    int c = blk & (NC - 1);
    int bh = blk >> 5;
    int b = bh >> 4, h = bh & 15;
    __shared__ __align__(16) float Ks[64][68];
    __shared__ __align__(16) float Vs[64][68];
    int tid = threadIdx.x;
    int rrow = tid >> 4;
    int rc4 = (tid & 15) * 4;
#pragma unroll
    for (int r = 0; r < 4; r++) {
        int row = rrow + r * 16;
        int gidx = (b * TT + c * CC + row) * QS + h * DH + rc4;
        ushort4 k4 = *(const ushort4*)&k[gidx];
        ushort4 v4 = *(const ushort4*)&v[gidx];
        *(float4*)&Ks[row][rc4] =
            make_float4(bf2f(k4.x), bf2f(k4.y), bf2f(k4.z), bf2f(k4.w));
        *(float4*)&Vs[row][rc4] =
            make_float4(bf2f(v4.x), bf2f(v4.y), bf2f(v4.z), bf2f(v4.w));
    }
    __syncthreads();
    int d0 = (tid >> 4) * 4, e0 = (tid & 15) * 4;
    float acc[4][4] = {};
    for (int t = 0; t < CC; t++) {
        float4 a4 = *(const float4*)&Ks[t][d0];
        float4 b4 = *(const float4*)&Vs[t][e0];
        float aa[4] = {a4.x, a4.y, a4.z, a4.w};
        float bb[4] = {b4.x, b4.y, b4.z, b4.w};
#pragma unroll
        for (int i = 0; i < 4; i++)
#pragma unroll
            for (int j = 0; j < 4; j++) acc[i][j] += aa[i] * bb[j];
    }
    size_t sbase = (size_t)blk * 4096;
#pragma unroll
    for (int i = 0; i < 4; i++)
        *(float4*)&S[sbase + (d0 + i) * 64 + e0] =
            make_float4(acc[i][0], acc[i][1], acc[i][2], acc[i][3]);
    if (tid < 64) {
        float s = 0.f;
        for (int t = 0; t < CC; t++) s += Ks[t][tid];
        z[(size_t)blk * 64 + tid] = s;
    }
}

// ---------------------------------------------------------------------------
// Parallel in-place exclusive prefix over chunks. grid = B*H*16 blocks.
// Block (bh, seg) scans S elements [seg*256, seg*256+256); seg==0 also does z.
// ---------------------------------------------------------------------------
__global__ __launch_bounds__(256) void prefix_par(
    float* __restrict__ S, float* __restrict__ z)
{
    int bh = blockIdx.x >> 4;
    int seg = blockIdx.x & 15;
    int e = seg * 256 + threadIdx.x;
    size_t base = (size_t)bh * NC * 4096 + e;
    float run = 0.f;
    for (int c = 0; c < NC; c++) {
        float t = S[base + (size_t)c * 4096];
        S[base + (size_t)c * 4096] = run;
        run += t;
    }
    if (seg == 0 && threadIdx.x < 64) {
        size_t zb = (size_t)bh * NC * 64 + threadIdx.x;
        float rz = 0.f;
        for (int c = 0; c < NC; c++) {
            float t = z[zb + c * 64];
            z[zb + c * 64] = rz;
            rz += t;
        }
    }
}

// ---------------------------------------------------------------------------
// Fused chunk attention (fp32 math, bf16 q/k/v in, bf16 out).
// ---------------------------------------------------------------------------
__global__ __launch_bounds__(256) void attn_chunk(
    const ushort* __restrict__ q, const ushort* __restrict__ k,
    const ushort* __restrict__ v, const float* __restrict__ Sx,
    const float* __restrict__ zx, ushort* __restrict__ ob)
{
    __shared__ __align__(16) float sm[13568];
    float* QT = sm;            // [64][65] q transposed
    float* KS = sm + 4160;     // [64][65] k rows; later ALT[s*64+t]
    float* SP = sm + 8320;     // [64][64] S_prefix; later VS[s*64+e]
    float* DP = sm + 12416;    // [64][16]
    float* ZP = sm + 13440;    // [64]
    float* DI = sm + 13504;    // [64]

    int tid = threadIdx.x;
    int blk = blockIdx.x;
    int c = blk & (NC - 1);
    int bh = blk >> 5;
    int b = bh >> 4, h = bh & 15;

    int rrow = tid >> 4;
    int rc4 = (tid & 15) * 4;

    // phase 1: load Q (transposed), K rows, zp
#pragma unroll
    for (int r = 0; r < 4; r++) {
        int row = rrow + r * 16;
        int gidx = (b * TT + c * CC + row) * QS + h * DH + rc4;
        ushort4 q4 = *(const ushort4*)&q[gidx];
        QT[(rc4 + 0) * 65 + row] = bf2f(q4.x);
        QT[(rc4 + 1) * 65 + row] = bf2f(q4.y);
        QT[(rc4 + 2) * 65 + row] = bf2f(q4.z);
        QT[(rc4 + 3) * 65 + row] = bf2f(q4.w);
        ushort4 k4 = *(const ushort4*)&k[gidx];
        KS[row * 65 + rc4 + 0] = bf2f(k4.x);
        KS[row * 65 + rc4 + 1] = bf2f(k4.y);
        KS[row * 65 + rc4 + 2] = bf2f(k4.z);
        KS[row * 65 + rc4 + 3] = bf2f(k4.w);
    }
    if (tid < 64) ZP[tid] = zx[(size_t)blk * 64 + tid];
    __syncthreads();

    // phase 2: A[t][s] = q_t . k_s
    int t0 = (tid >> 4) * 4, s0 = (tid & 15) * 4;
    float acc[4][4] = {};
    for (int d = 0; d < 64; d++) {
        float qa[4], kb[4];
#pragma unroll
        for (int i = 0; i < 4; i++) qa[i] = QT[d * 65 + t0 + i];
#pragma unroll
        for (int j = 0; j < 4; j++) kb[j] = KS[(s0 + j) * 65 + d];
#pragma unroll
        for (int i = 0; i < 4; i++)
#pragma unroll
            for (int j = 0; j < 4; j++) acc[i][j] += qa[i] * kb[j];
    }
#pragma unroll
    for (int i = 0; i < 4; i++) {
        float rs = 0.f;
#pragma unroll
        for (int j = 0; j < 4; j++)
            if (s0 + j <= t0 + i) rs += acc[i][j];
        DP[(t0 + i) * 16 + (tid & 15)] = rs;
    }
    __syncthreads();

    // phase 3: load S_prefix; threads<64 compute 1/den
#pragma unroll
    for (int r = 0; r < 4; r++) {
        int row = rrow + r * 16;
        *(float4*)&SP[row * 64 + rc4] =
            *(const float4*)&Sx[(size_t)blk * 4096 + row * 64 + rc4];
    }
    if (tid < 64) {
        int t = tid;
        float s = 0.f;
        for (int d = 0; d < 64; d++) s += QT[d * 65 + t] * ZP[d];
#pragma unroll
        for (int p = 0; p < 16; p++) s += DP[t * 16 + p];
        DI[t] = 1.f / fmaxf(s, EPSV);
    }
    __syncthreads();

    // phase 4: inter-chunk o[e] = sum_d q_t[d] * Sp[d][e]
    int t = tid >> 2;
    int e0 = (tid & 3) * 16;
    float o[16] = {};
    for (int d = 0; d < 64; d++) {
        float qv = QT[d * 65 + t];
#pragma unroll
        for (int jj = 0; jj < 4; jj++) {
            float4 s4 = *(const float4*)&SP[d * 64 + e0 + jj * 4];
            o[jj * 4 + 0] += qv * s4.x;
            o[jj * 4 + 1] += qv * s4.y;
            o[jj * 4 + 2] += qv * s4.z;
            o[jj * 4 + 3] += qv * s4.w;
        }
    }
    __syncthreads();

    // phase 5: overlay A -> KS (transposed), V -> SP
    float* ALT = KS;
    float* VS = SP;
#pragma unroll
    for (int i = 0; i < 4; i++)
#pragma unroll
        for (int j = 0; j < 4; j++)
            ALT[(s0 + j) * 64 + (t0 + i)] = acc[i][j];
#pragma unroll
    for (int r = 0; r < 4; r++) {
        int row = rrow + r * 16;
        int gidx = (b * TT + c * CC + row) * QS + h * DH + rc4;
        ushort4 v4 = *(const ushort4*)&v[gidx];
        *(float4*)&VS[row * 64 + rc4] =
            make_float4(bf2f(v4.x), bf2f(v4.y), bf2f(v4.z), bf2f(v4.w));
    }
    __syncthreads();

    // phase 6: intra-chunk causal + divide + bf16 store
    for (int s = 0; s <= t; s++) {
        float av = ALT[s * 64 + t];
#pragma unroll
        for (int jj = 0; jj < 4; jj++) {
            float4 v4 = *(const float4*)&VS[s * 64 + e0 + jj * 4];
            o[jj * 4 + 0] += av * v4.x;
            o[jj * 4 + 1] += av * v4.y;
            o[jj * 4 + 2] += av * v4.z;
            o[jj * 4 + 3] += av * v4.w;
        }
    }
    float di = DI[t];
    int gidx = (b * TT + c * CC + t) * DD + h * DH + e0;
#pragma unroll
    for (int jj = 0; jj < 4; jj++) {
        *(ushort4*)&ob[gidx + jj * 4] = make_ushort4(
            f2bf(o[jj * 4 + 0] * di), f2bf(o[jj * 4 + 1] * di),
            f2bf(o[jj * 4 + 2] * di), f2bf(o[jj * 4 + 3] * di));
    }
}

// ---------------------------------------------------------------------------
extern "C" void kernel_launch(void* const* d_in, const int* in_sizes, int n_in,
                              void* d_out, int out_size, void* d_ws, size_t ws_size,
                              hipStream_t stream) {
    const float* x  = (const float*)d_in[0];
    const float* Wq = (const float*)d_in[1];
    const float* bq = (const float*)d_in[2];
    const float* Wk = (const float*)d_in[3];
    const float* bk = (const float*)d_in[4];
    const float* Wv = (const float*)d_in[5];
    const float* bv = (const float*)d_in[6];
    const float* Wo = (const float*)d_in[7];
    const float* bo = (const float*)d_in[8];
    float* out = (float*)d_out;

    char* ws = (char*)d_ws;
    ushort* xb    = (ushort*)(ws + 0);          //  8388608 B (4096x1024 bf16)
    ushort* Wqkvb = (ushort*)(ws + 8388608);    //  6291456 B (3072x1024 bf16)
    ushort* Wob   = (ushort*)(ws + 14680064);   //  2097152 B
    float*  biasq = (float*)(ws + 16777216);    //    12288 B
    ushort* qkvb  = (ushort*)(ws + 16789504);   // 25165824 B (4096x3072 bf16)
    float*  S     = (float*)(ws + 41955328);    // 16777216 B
    float*  z     = (float*)(ws + 58732544);    //   262144 B
    ushort* attnb = (ushort*)(ws + 0);          // reuse xb region (dead after QKV gemm)

    convert_pack<<<4096, 256, 0, stream>>>(x, Wq, Wk, Wv, Wo, bq, bk, bv,
                                           xb, Wqkvb, Wob, biasq);
    // fused QKV projection -> bf16: cols 0-1023=q, 1024-2047=k, 2048-3071=v
    gemm_mfma<true><<<dim3(3072 / BN, BT / BM), 256, 0, stream>>>(
        xb, Wqkvb, biasq, qkvb, BT, 3072, DD, 2048);
    const ushort* qp = qkvb;
    const ushort* kp = qkvb + 1024;
    const ushort* vp = qkvb + 2048;
    chunk_kv<<<BB * HH * NC, 256, 0, stream>>>(kp, vp, S, z);
    prefix_par<<<BB * HH * 16, 256, 0, stream>>>(S, z);
    attn_chunk<<<BB * HH * NC, 256, 0, stream>>>(qp, kp, vp, S, z, attnb);
    gemm_mfma<false><<<dim3(DD / BN, BT / BM), 256, 0, stream>>>(
        attnb, Wob, bo, out, BT, DD, DD, 0);
}

// Round 4
// 182.632 us; speedup vs baseline: 3.7428x; 1.2171x over previous
//
#include <hip/hip_runtime.h>
#include <math.h>

// Problem constants
#define BB 2
#define TT 2048
#define DD 1024
#define HH 16
#define DH 64
#define BT (BB*TT)          // 4096
#define CC 64               // chunk length
#define NC (TT/CC)          // 32 chunks
#define EPSV 1e-6f
#define QS 3072             // fused qkv row stride (bf16)

typedef __attribute__((ext_vector_type(8))) short short8;
typedef __attribute__((ext_vector_type(4))) float f32x4;

__device__ inline ushort f2bf(float f) {
    unsigned u = __float_as_uint(f);
    u = (u + 0x7fffu + ((u >> 16) & 1u)) >> 16;   // RNE
    return (ushort)u;
}
__device__ inline float bf2f(ushort u) {
    return __uint_as_float(((unsigned)u) << 16);
}

__device__ inline void async16(const void* g, void* l) {
    __builtin_amdgcn_global_load_lds(
        (const __attribute__((address_space(1))) void*)g,
        (__attribute__((address_space(3))) void*)l, 16, 0, 0);
}

// ---------------------------------------------------------------------------
// Pack fp32 -> bf16: xb (4M), Wqkvb = [Wq;Wk;Wv] (3M), Wob (1M); biasq fp32.
// ---------------------------------------------------------------------------
__global__ __launch_bounds__(256) void convert_pack(
    const float* __restrict__ x, const float* __restrict__ Wq,
    const float* __restrict__ Wk, const float* __restrict__ Wv,
    const float* __restrict__ Wo, const float* __restrict__ bq,
    const float* __restrict__ bk, const float* __restrict__ bv,
    ushort* __restrict__ xb, ushort* __restrict__ Wqkvb,
    ushort* __restrict__ Wob, float* __restrict__ biasq)
{
    int i = blockIdx.x * 256 + threadIdx.x;      // 0..1048575
    int idx = i * 8;
    const float* src;
    ushort* dst;
    if (idx < 4194304) { src = x + idx; dst = xb + idx; }
    else if (idx < 7340032) {
        int r = idx - 4194304;
        int w = r >> 20;
        int o = r & 1048575;
        src = (w == 0 ? Wq : (w == 1 ? Wk : Wv)) + o;
        dst = Wqkvb + r;
    } else {
        int r = idx - 7340032;
        src = Wo + r; dst = Wob + r;
    }
    float4 f0 = *(const float4*)src;
    float4 f1 = *(const float4*)(src + 4);
    *(ushort4*)dst = make_ushort4(f2bf(f0.x), f2bf(f0.y), f2bf(f0.z), f2bf(f0.w));
    *(ushort4*)(dst + 4) = make_ushort4(f2bf(f1.x), f2bf(f1.y), f2bf(f1.z), f2bf(f1.w));
    if (i < 3072)
        biasq[i] = (i < 1024) ? bq[i] : (i < 2048) ? bk[i - 1024] : bv[i - 2048];
}

// ---------------------------------------------------------------------------
// MFMA bf16 GEMM (unchanged from round 3): C = act(A·Wᵀ + bias)
// ---------------------------------------------------------------------------
#define BM 128
#define BN 128
#define BK 32

template<bool OBF16>
__global__ __launch_bounds__(256) void gemm_mfma(
    const ushort* __restrict__ A, const ushort* __restrict__ W,
    const float* __restrict__ bias, void* __restrict__ Cv,
    int M, int N, int K, int act_limit)
{
    constexpr int SMEM_US = OBF16 ? (128 * 132) : (BM * BK + BN * BK);
    __shared__ __align__(16) ushort smem[SMEM_US];
    ushort* As = smem;
    ushort* Bs = smem + BM * BK;
    int tid = threadIdx.x;
    int lane = tid & 63, wave = tid >> 6;
    int m0 = blockIdx.y * BM, n0 = blockIdx.x * BN;
    int wm = (wave >> 1) * 64, wn = (wave & 1) * 64;

    int p = lane & 3;
    int r0 = (wave * 2 + 0) * 16 + (lane >> 2);
    int r1 = (wave * 2 + 1) * 16 + (lane >> 2);
    int kg0 = p ^ ((r0 >> 1) & 3);
    int kg1 = p ^ ((r1 >> 1) & 3);
    const ushort* gA0 = A + (size_t)(m0 + r0) * K + kg0 * 8;
    const ushort* gA1 = A + (size_t)(m0 + r1) * K + kg1 * 8;
    const ushort* gB0 = W + (size_t)(n0 + r0) * K + kg0 * 8;
    const ushort* gB1 = W + (size_t)(n0 + r1) * K + kg1 * 8;
    ushort* lA0 = &As[r0 * BK + p * 8];
    ushort* lA1 = &As[r1 * BK + p * 8];
    ushort* lB0 = &Bs[r0 * BK + p * 8];
    ushort* lB1 = &Bs[r1 * BK + p * 8];

    int fr = lane & 15;
    int g = lane >> 4;
    int pk = (g ^ ((fr >> 1) & 3)) * 8;
    const ushort* aBase = &As[(wm + fr) * BK + pk];
    const ushort* bBase = &Bs[(wn + fr) * BK + pk];

    f32x4 acc[4][4];
#pragma unroll
    for (int i = 0; i < 4; i++)
#pragma unroll
        for (int j = 0; j < 4; j++) acc[i][j] = (f32x4){0.f, 0.f, 0.f, 0.f};

    for (int kt = 0; kt < K; kt += BK) {
        async16(gA0 + kt, lA0);
        async16(gA1 + kt, lA1);
        async16(gB0 + kt, lB0);
        async16(gB1 + kt, lB1);
        __syncthreads();
        short8 af[4], bf[4];
#pragma unroll
        for (int i = 0; i < 4; i++) af[i] = *(const short8*)(aBase + i * 16 * BK);
#pragma unroll
        for (int j = 0; j < 4; j++) bf[j] = *(const short8*)(bBase + j * 16 * BK);
#pragma unroll
        for (int i = 0; i < 4; i++)
#pragma unroll
            for (int j = 0; j < 4; j++)
                acc[i][j] = __builtin_amdgcn_mfma_f32_16x16x32_bf16(
                    af[i], bf[j], acc[i][j], 0, 0, 0);
        __syncthreads();
    }

    if (OBF16) {
        ushort* Cs = smem;   // 128 x 132
#pragma unroll
        for (int j = 0; j < 4; j++) {
            int colL = wn + j * 16 + fr;
            float bv_ = bias[n0 + colL];
            bool act = (n0 + colL) < act_limit;
#pragma unroll
            for (int i = 0; i < 4; i++) {
                int rowL = wm + i * 16 + g * 4;
#pragma unroll
                for (int r = 0; r < 4; r++) {
                    float v = acc[i][j][r] + bv_;
                    if (act) v = (v > 0.f) ? (v + 1.f) : expf(v);
                    Cs[(rowL + r) * 132 + colL] = f2bf(v);
                }
            }
        }
        __syncthreads();
        ushort* C = (ushort*)Cv;
        int orow = tid >> 4, ocol = (tid & 15) * 8;
#pragma unroll
        for (int it = 0; it < 8; it++) {
            int rr = orow + it * 16;
            ushort4 lo = *(const ushort4*)&Cs[rr * 132 + ocol];
            ushort4 hi = *(const ushort4*)&Cs[rr * 132 + ocol + 4];
            ushort pk8[8] = {lo.x, lo.y, lo.z, lo.w, hi.x, hi.y, hi.z, hi.w};
            *(uint4*)&C[(size_t)(m0 + rr) * N + n0 + ocol] = *(uint4*)pk8;
        }
    } else {
        float* C = (float*)Cv;
#pragma unroll
        for (int j = 0; j < 4; j++) {
            int col = n0 + wn + j * 16 + fr;
            float bv_ = bias[col];
            bool act = col < act_limit;
#pragma unroll
            for (int i = 0; i < 4; i++) {
                int rowb = m0 + wm + i * 16 + g * 4;
#pragma unroll
                for (int r = 0; r < 4; r++) {
                    float v = acc[i][j][r] + bv_;
                    if (act) v = (v > 0.f) ? (v + 1.f) : expf(v);
                    C[(size_t)(rowb + r) * N + col] = v;
                }
            }
        }
    }
}

// ---------------------------------------------------------------------------
// Per-chunk Sᵀ_ext[e][d] = Σ_t V_ext[t][e]·K[t][d] via MFMA, e∈0..64 (row 64 = z).
// grid = B*H*NC. Output fp32, 5120 floats/block (rows 65..79 not stored).
// ---------------------------------------------------------------------------
__global__ __launch_bounds__(256) void chunk_kv_mfma(
    const ushort* __restrict__ qkv, float* __restrict__ S)
{
    __shared__ __align__(16) ushort sm[9216];   // KT 64x64 @0, VT 80x64 @4096
    int tid = threadIdx.x, lane = tid & 63, wave = tid >> 6;
    int blk = blockIdx.x;
    int c = blk & (NC - 1);
    int bh = blk >> 5;
    int b = bh >> 4, h = bh & 15;
    size_t rowbase = (size_t)(b * TT + c * CC) * QS + h * DH;

    int rrow = tid >> 4, rc4 = (tid & 15) * 4;
#pragma unroll
    for (int r = 0; r < 4; r++) {
        int row = rrow + r * 16;
        ushort4 k4 = *(const ushort4*)&qkv[rowbase + (size_t)row * QS + 1024 + rc4];
        ushort4 v4 = *(const ushort4*)&qkv[rowbase + (size_t)row * QS + 2048 + rc4];
#pragma unroll
        for (int j = 0; j < 4; j++) {
            int d = rc4 + j;
            int pos = (row >> 3) ^ (d & 7);
            sm[0    + d * 64 + pos * 8 + (row & 7)] = ((const ushort*)&k4)[j];
            sm[4096 + d * 64 + pos * 8 + (row & 7)] = ((const ushort*)&v4)[j];
        }
    }
    if (tid < 16) {   // ones row e=64 of VT (swizzle-invariant: constant row)
        ushort4 one4 = make_ushort4(0x3F80, 0x3F80, 0x3F80, 0x3F80);
        *(ushort4*)&sm[4096 + 64 * 64 + tid * 4] = one4;
    }
    __syncthreads();

    int fr = lane & 15, g = lane >> 4;
    // b-frags: KT rows (cols d of output), wave covers d = wave*16 + fr
    short8 bk_[2];
#pragma unroll
    for (int kt = 0; kt < 2; kt++) {
        int row = wave * 16 + fr;
        int kg = kt * 4 + g;
        bk_[kt] = *(const short8*)&sm[0 + row * 64 + (kg ^ (row & 7)) * 8];
    }
    f32x4 acc[5];
#pragma unroll
    for (int it = 0; it < 5; it++) acc[it] = (f32x4){0.f, 0.f, 0.f, 0.f};
#pragma unroll
    for (int it = 0; it < 5; it++) {
        int arow = it * 16 + fr;
#pragma unroll
        for (int kt = 0; kt < 2; kt++) {
            int kg = kt * 4 + g;
            short8 av = *(const short8*)&sm[4096 + arow * 64 + (kg ^ (arow & 7)) * 8];
            acc[it] = __builtin_amdgcn_mfma_f32_16x16x32_bf16(av, bk_[kt], acc[it], 0, 0, 0);
        }
    }
    size_t sb = (size_t)blk * 5120;
#pragma unroll
    for (int it = 0; it < 4; it++)
#pragma unroll
        for (int r = 0; r < 4; r++) {
            int e = it * 16 + g * 4 + r;
            S[sb + e * 64 + wave * 16 + fr] = acc[it][r];
        }
    if (g == 0) S[sb + 64 * 64 + wave * 16 + fr] = acc[4][0];   // z row (e=64)
}

// ---------------------------------------------------------------------------
// Exclusive prefix over chunks of Sᵀ_ext; emits bf16 pre-swizzled SpT (80 rows,
// rows 65..79 zero). grid = B*H*20 blocks.
// ---------------------------------------------------------------------------
__global__ __launch_bounds__(256) void prefix_scan(
    const float* __restrict__ S, ushort* __restrict__ SpT)
{
    int bh = blockIdx.x / 20;
    int seg = blockIdx.x % 20;
    int idx = seg * 256 + threadIdx.x;   // 0..5119
    int e = idx >> 6, d = idx & 63;
    size_t base = (size_t)bh * NC * 5120;
    int pos = (d >> 3) ^ (e & 7);
    size_t woff = (size_t)e * 64 + pos * 8 + (d & 7);
    if (e <= 64) {
        float run = 0.f;
        for (int c = 0; c < NC; c++) {
            size_t boff = base + (size_t)c * 5120;
            float t = S[boff + idx];
            SpT[boff + woff] = f2bf(run);
            run += t;
        }
    } else {
        for (int c = 0; c < NC; c++)
            SpT[base + (size_t)c * 5120 + woff] = 0;
    }
}

// ---------------------------------------------------------------------------
// MFMA chunk attention. Per block (b,h,c):
//   A = Q·Kᵀ ; P = causal-mask(A) (bf16, LDS)
//   O = Q·Sp_ext + P·V_ext   (col 64 = denominator: q·zp + rowsum P)
//   out[t][e] = O[t][e] / max(O[t][64], eps)   -> bf16
// LDS (ushort idx): Q@0 (4096), K/P@4096 (4096), SpT@8192 (5120, later O-stage
// stride 72), VT@13312 (5120). 36864 B total. 8-quad XOR swizzle everywhere.
// ---------------------------------------------------------------------------
__global__ __launch_bounds__(256) void attn_mfma(
    const ushort* __restrict__ qkv, const ushort* __restrict__ SpT,
    ushort* __restrict__ ob)
{
    __shared__ __align__(16) ushort sm[18432];
    const int LQ = 0, LK = 4096, LSP = 8192, LVT = 13312;
    int tid = threadIdx.x, lane = tid & 63, wave = tid >> 6;
    int blk = blockIdx.x;
    int c = blk & (NC - 1);
    int bh = blk >> 5;
    int b = bh >> 4, h = bh & 15;
    size_t rowbase = (size_t)(b * TT + c * CC) * QS + h * DH;

    // stage Q,K via async16 with global-side swizzle (LDS linear per slot)
#pragma unroll
    for (int r = 0; r < 2; r++) {
        int slot = (r * 4 + wave) * 64 + lane;
        int row = slot >> 3, p = slot & 7;
        int kg = p ^ (row & 7);
        const ushort* gq = qkv + rowbase + (size_t)row * QS + kg * 8;
        async16(gq, &sm[LQ + slot * 8]);
        async16(gq + 1024, &sm[LK + slot * 8]);
    }
    // stage SpT (pre-swizzled in global): flat copy, 640 slots
    {
        size_t spbase = (size_t)blk * 5120;
        int slot = wave * 64 + lane;
        async16(SpT + spbase + slot * 8, &sm[LSP + slot * 8]);
        async16(SpT + spbase + (slot + 256) * 8, &sm[LSP + (slot + 256) * 8]);
        if (wave < 2) {
            int s2 = 512 + wave * 64 + lane;
            async16(SpT + spbase + s2 * 8, &sm[LSP + s2 * 8]);
        }
    }
    // stage V transposed (scatter)
    {
        int rrow = tid >> 4, rc4 = (tid & 15) * 4;
#pragma unroll
        for (int r = 0; r < 4; r++) {
            int row = rrow + r * 16;
            ushort4 v4 = *(const ushort4*)&qkv[rowbase + (size_t)row * QS + 2048 + rc4];
#pragma unroll
            for (int j = 0; j < 4; j++) {
                int e = rc4 + j;
                int pos = (row >> 3) ^ (e & 7);
                sm[LVT + e * 64 + pos * 8 + (row & 7)] = ((const ushort*)&v4)[j];
            }
        }
        if (tid < 16) {   // ones row e=64
            ushort4 one4 = make_ushort4(0x3F80, 0x3F80, 0x3F80, 0x3F80);
            *(ushort4*)&sm[LVT + 64 * 64 + tid * 4] = one4;
        }
    }
    __syncthreads();

    int fr = lane & 15, g = lane >> 4;
    int mrow = wave * 16 + fr;            // this wave's A-operand row (t)

    // Q a-frags (reused in steps A and B)
    short8 aq[2];
#pragma unroll
    for (int kt = 0; kt < 2; kt++) {
        int kg = kt * 4 + g;
        aq[kt] = *(const short8*)&sm[LQ + mrow * 64 + (kg ^ (mrow & 7)) * 8];
    }

    // Step A: A = Q·Kᵀ (wave's 16 rows x 64 cols)
    f32x4 accA[4];
#pragma unroll
    for (int jt = 0; jt < 4; jt++) accA[jt] = (f32x4){0.f, 0.f, 0.f, 0.f};
#pragma unroll
    for (int jt = 0; jt < 4; jt++) {
        int nrow = jt * 16 + fr;
#pragma unroll
        for (int kt = 0; kt < 2; kt++) {
            int kg = kt * 4 + g;
            short8 bk_ = *(const short8*)&sm[LK + nrow * 64 + (kg ^ (nrow & 7)) * 8];
            accA[jt] = __builtin_amdgcn_mfma_f32_16x16x32_bf16(aq[kt], bk_, accA[jt], 0, 0, 0);
        }
    }
    __syncthreads();   // all K reads done before P overwrites LK

    // mask -> P (bf16) into LK region
#pragma unroll
    for (int jt = 0; jt < 4; jt++) {
        int s = jt * 16 + fr;
#pragma unroll
        for (int r = 0; r < 4; r++) {
            int t = wave * 16 + g * 4 + r;
            float pv = (s <= t) ? accA[jt][r] : 0.f;
            int pos = (s >> 3) ^ (t & 7);
            sm[LK + t * 64 + pos * 8 + (s & 7)] = f2bf(pv);
        }
    }

    // Step B: O += Q·Sp_ext (5 j-tiles; col 64 = q·zp)
    f32x4 acc[5];
#pragma unroll
    for (int jt = 0; jt < 5; jt++) acc[jt] = (f32x4){0.f, 0.f, 0.f, 0.f};
#pragma unroll
    for (int jt = 0; jt < 5; jt++) {
        int nrow = jt * 16 + fr;
#pragma unroll
        for (int kt = 0; kt < 2; kt++) {
            int kg = kt * 4 + g;
            short8 bsp = *(const short8*)&sm[LSP + nrow * 64 + (kg ^ (nrow & 7)) * 8];
            acc[jt] = __builtin_amdgcn_mfma_f32_16x16x32_bf16(aq[kt], bsp, acc[jt], 0, 0, 0);
        }
    }
    __syncthreads();   // P visible to all; SpT reads complete (O-stage may overlay)

    // Step C: O += P·V_ext (col 64 += rowsum P)
    short8 ap[2];
#pragma unroll
    for (int kt = 0; kt < 2; kt++) {
        int kg = kt * 4 + g;
        ap[kt] = *(const short8*)&sm[LK + mrow * 64 + (kg ^ (mrow & 7)) * 8];
    }
#pragma unroll
    for (int jt = 0; jt < 5; jt++) {
        int nrow = jt * 16 + fr;
#pragma unroll
        for (int kt = 0; kt < 2; kt++) {
            int kg = kt * 4 + g;
            short8 bvt = *(const short8*)&sm[LVT + nrow * 64 + (kg ^ (nrow & 7)) * 8];
            acc[jt] = __builtin_amdgcn_mfma_f32_16x16x32_bf16(ap[kt], bvt, acc[jt], 0, 0, 0);
        }
    }

    // denominator: col 64 lives in acc[4][r] of lanes fr==0; broadcast via shfl
    int srcl = g * 16;
    float rdi[4];
#pragma unroll
    for (int r = 0; r < 4; r++) {
        float den = __shfl(acc[4][r], srcl, 64);
        rdi[r] = 1.f / fmaxf(den, EPSV);
    }
    // write O bf16 to stage (stride 72, overlays LSP region)
#pragma unroll
    for (int jt = 0; jt < 4; jt++) {
        int e = jt * 16 + fr;
#pragma unroll
        for (int r = 0; r < 4; r++) {
            int t = wave * 16 + g * 4 + r;
            sm[LSP + t * 72 + e] = f2bf(acc[jt][r] * rdi[r]);
        }
    }
    __syncthreads();

    // coalesced 16B global stores
#pragma unroll
    for (int it = 0; it < 2; it++) {
        int slot = it * 256 + tid;
        int row = slot >> 3, ch = slot & 7;
        ushort4 lo = *(const ushort4*)&sm[LSP + row * 72 + ch * 8];
        ushort4 hi = *(const ushort4*)&sm[LSP + row * 72 + ch * 8 + 4];
        ushort pk8[8] = {lo.x, lo.y, lo.z, lo.w, hi.x, hi.y, hi.z, hi.w};
        *(uint4*)&ob[(size_t)(b * TT + c * CC + row) * DD + h * DH + ch * 8] = *(uint4*)pk8;
    }
}

// ---------------------------------------------------------------------------
extern "C" void kernel_launch(void* const* d_in, const int* in_sizes, int n_in,
                              void* d_out, int out_size, void* d_ws, size_t ws_size,
                              hipStream_t stream) {
    const float* x  = (const float*)d_in[0];
    const float* Wq = (const float*)d_in[1];
    const float* bq = (const float*)d_in[2];
    const float* Wk = (const float*)d_in[3];
    const float* bk = (const float*)d_in[4];
    const float* Wv = (const float*)d_in[5];
    const float* bv = (const float*)d_in[6];
    const float* Wo = (const float*)d_in[7];
    const float* bo = (const float*)d_in[8];
    float* out = (float*)d_out;

    char* ws = (char*)d_ws;
    ushort* xb    = (ushort*)(ws + 0);          //  8388608 B
    ushort* Wqkvb = (ushort*)(ws + 8388608);    //  6291456 B
    ushort* Wob   = (ushort*)(ws + 14680064);   //  2097152 B
    float*  biasq = (float*)(ws + 16777216);    //    12288 B
    ushort* qkvb  = (ushort*)(ws + 16789504);   // 25165824 B (4096x3072 bf16)
    float*  S     = (float*)(ws + 41955328);    // 20971520 B (1024x5120 f32)
    ushort* SpTb  = (ushort*)(ws + 62926848);   // 10485760 B (1024x5120 bf16)
    ushort* attnb = (ushort*)(ws + 0);          // reuse xb region

    convert_pack<<<4096, 256, 0, stream>>>(x, Wq, Wk, Wv, Wo, bq, bk, bv,
                                           xb, Wqkvb, Wob, biasq);
    gemm_mfma<true><<<dim3(3072 / BN, BT / BM), 256, 0, stream>>>(
        xb, Wqkvb, biasq, qkvb, BT, 3072, DD, 2048);
    chunk_kv_mfma<<<BB * HH * NC, 256, 0, stream>>>(qkvb, S);
    prefix_scan<<<BB * HH * 20, 256, 0, stream>>>(S, SpTb);
    attn_mfma<<<BB * HH * NC, 256, 0, stream>>>(qkvb, SpTb, attnb);
    gemm_mfma<false><<<dim3(DD / BN, BT / BM), 256, 0, stream>>>(
        attnb, Wob, bo, out, BT, DD, DD, 0);
}

// Round 5
// 165.903 us; speedup vs baseline: 4.1202x; 1.1008x over previous
//
#include <hip/hip_runtime.h>
#include <math.h>

// Problem constants
#define BB 2
#define TT 2048
#define DD 1024
#define HH 16
#define DH 64
#define BT (BB*TT)          // 4096
#define CC 64               // chunk length
#define NC (TT/CC)          // 32 chunks
#define EPSV 1e-6f
#define QS 3072             // fused qkv row stride (bf16)

typedef __attribute__((ext_vector_type(8))) short short8;
typedef __attribute__((ext_vector_type(4))) float f32x4;

__device__ inline ushort f2bf(float f) {
    unsigned u = __float_as_uint(f);
    u = (u + 0x7fffu + ((u >> 16) & 1u)) >> 16;   // RNE
    return (ushort)u;
}
__device__ inline float bf2f(ushort u) {
    return __uint_as_float(((unsigned)u) << 16);
}

__device__ inline void async16(const void* g, void* l) {
    __builtin_amdgcn_global_load_lds(
        (const __attribute__((address_space(1))) void*)g,
        (__attribute__((address_space(3))) void*)l, 16, 0, 0);
}

// ---------------------------------------------------------------------------
// Pack fp32 -> bf16: xb (4M), Wqkvb = [Wq;Wk;Wv] (3M), Wob (1M); biasq fp32.
// ---------------------------------------------------------------------------
__global__ __launch_bounds__(256) void convert_pack(
    const float* __restrict__ x, const float* __restrict__ Wq,
    const float* __restrict__ Wk, const float* __restrict__ Wv,
    const float* __restrict__ Wo, const float* __restrict__ bq,
    const float* __restrict__ bk, const float* __restrict__ bv,
    ushort* __restrict__ xb, ushort* __restrict__ Wqkvb,
    ushort* __restrict__ Wob, float* __restrict__ biasq)
{
    int i = blockIdx.x * 256 + threadIdx.x;      // 0..1048575
    int idx = i * 8;
    const float* src;
    ushort* dst;
    if (idx < 4194304) { src = x + idx; dst = xb + idx; }
    else if (idx < 7340032) {
        int r = idx - 4194304;
        int w = r >> 20;
        int o = r & 1048575;
        src = (w == 0 ? Wq : (w == 1 ? Wk : Wv)) + o;
        dst = Wqkvb + r;
    } else {
        int r = idx - 7340032;
        src = Wo + r; dst = Wob + r;
    }
    float4 f0 = *(const float4*)src;
    float4 f1 = *(const float4*)(src + 4);
    *(ushort4*)dst = make_ushort4(f2bf(f0.x), f2bf(f0.y), f2bf(f0.z), f2bf(f0.w));
    *(ushort4*)(dst + 4) = make_ushort4(f2bf(f1.x), f2bf(f1.y), f2bf(f1.z), f2bf(f1.w));
    if (i < 3072)
        biasq[i] = (i < 1024) ? bq[i] : (i < 2048) ? bk[i - 1024] : bv[i - 2048];
}

// ---------------------------------------------------------------------------
// MFMA bf16 GEMM, BK=64: C = act(A·Wᵀ + bias).
// TBM x TBN tile, 4 waves (2x2 grid of (TBM/2)x(TBN/2) wave-tiles).
// LDS rows = 64 bf16 = 128 B = 8 x 16B groups; group kg of row r stored at
// position kg ^ (r&7) (global-side swizzle; each 16-lane read phase covers
// all 8 bank-quads twice -> conflict-free).
// OBF16: bf16 output via LDS transpose (requires TBM=TBN=128); else fp32 direct.
// ---------------------------------------------------------------------------
template<int TBM, int TBN, bool OBF16>
__global__ __launch_bounds__(256) void gemm_mfma(
    const ushort* __restrict__ A, const ushort* __restrict__ W,
    const float* __restrict__ bias, void* __restrict__ Cv,
    int M, int N, int K, int act_limit)
{
    constexpr int IT = TBM / 32, JT = TBN / 32;      // 16x16 tiles per wave
    constexpr int APT = TBM * 8 / 256;               // 16B staging slots/thread
    constexpr int BPT = TBN * 8 / 256;
    constexpr int STAGE_US = (TBM + TBN) * 64;
    constexpr int SMEM_US = (OBF16 && TBM * 132 > STAGE_US) ? TBM * 132 : STAGE_US;
    __shared__ __align__(16) ushort smem[SMEM_US];
    ushort* As = smem;
    ushort* Bs = smem + TBM * 64;
    int tid = threadIdx.x;
    int lane = tid & 63, wave = tid >> 6;
    int m0 = blockIdx.y * TBM, n0 = blockIdx.x * TBN;
    int wm = (wave >> 1) * (TBM / 2), wn = (wave & 1) * (TBN / 2);

    const ushort* gA[APT]; ushort* lA[APT];
    const ushort* gB[BPT]; ushort* lB[BPT];
#pragma unroll
    for (int s = 0; s < APT; s++) {
        int slot = s * 256 + tid;
        int row = slot >> 3, p = slot & 7, kg = p ^ (row & 7);
        gA[s] = A + (size_t)(m0 + row) * K + kg * 8;
        lA[s] = &As[slot * 8];
    }
#pragma unroll
    for (int s = 0; s < BPT; s++) {
        int slot = s * 256 + tid;
        int row = slot >> 3, p = slot & 7, kg = p ^ (row & 7);
        gB[s] = W + (size_t)(n0 + row) * K + kg * 8;
        lB[s] = &Bs[slot * 8];
    }

    int fr = lane & 15, g = lane >> 4;

    f32x4 acc[IT][JT];
#pragma unroll
    for (int i = 0; i < IT; i++)
#pragma unroll
        for (int j = 0; j < JT; j++) acc[i][j] = (f32x4){0.f, 0.f, 0.f, 0.f};

    for (int kt = 0; kt < K; kt += 64) {
#pragma unroll
        for (int s = 0; s < APT; s++) async16(gA[s] + kt, lA[s]);
#pragma unroll
        for (int s = 0; s < BPT; s++) async16(gB[s] + kt, lB[s]);
        __syncthreads();
#pragma unroll
        for (int ks = 0; ks < 2; ks++) {
            int kg = ks * 4 + g;
            short8 af[IT], bf[JT];
#pragma unroll
            for (int i = 0; i < IT; i++) {
                int mr = wm + i * 16 + fr;
                af[i] = *(const short8*)&As[mr * 64 + (kg ^ (mr & 7)) * 8];
            }
#pragma unroll
            for (int j = 0; j < JT; j++) {
                int nr = wn + j * 16 + fr;
                bf[j] = *(const short8*)&Bs[nr * 64 + (kg ^ (nr & 7)) * 8];
            }
#pragma unroll
            for (int i = 0; i < IT; i++)
#pragma unroll
                for (int j = 0; j < JT; j++)
                    acc[i][j] = __builtin_amdgcn_mfma_f32_16x16x32_bf16(
                        af[i], bf[j], acc[i][j], 0, 0, 0);
        }
        __syncthreads();
    }

    // epilogue: C/D layout col=lane&15, row=(lane>>4)*4+reg
    if (OBF16) {
        ushort* Cs = smem;   // TBM x 132
#pragma unroll
        for (int j = 0; j < JT; j++) {
            int colL = wn + j * 16 + fr;
            float bv_ = bias[n0 + colL];
            bool act = (n0 + colL) < act_limit;
#pragma unroll
            for (int i = 0; i < IT; i++) {
                int rowL = wm + i * 16 + g * 4;
#pragma unroll
                for (int r = 0; r < 4; r++) {
                    float v = acc[i][j][r] + bv_;
                    if (act) v = (v > 0.f) ? (v + 1.f) : expf(v);
                    Cs[(rowL + r) * 132 + colL] = f2bf(v);
                }
            }
        }
        __syncthreads();
        ushort* C = (ushort*)Cv;
        int orow = tid >> 4, ocol = (tid & 15) * 8;
#pragma unroll
        for (int it = 0; it < TBM / 16; it++) {
            int rr = orow + it * 16;
            ushort4 lo = *(const ushort4*)&Cs[rr * 132 + ocol];
            ushort4 hi = *(const ushort4*)&Cs[rr * 132 + ocol + 4];
            ushort pk8[8] = {lo.x, lo.y, lo.z, lo.w, hi.x, hi.y, hi.z, hi.w};
            *(uint4*)&C[(size_t)(m0 + rr) * N + n0 + ocol] = *(uint4*)pk8;
        }
    } else {
        float* C = (float*)Cv;
#pragma unroll
        for (int j = 0; j < JT; j++) {
            int col = n0 + wn + j * 16 + fr;
            float bv_ = bias[col];
            bool act = col < act_limit;
#pragma unroll
            for (int i = 0; i < IT; i++) {
                int rowb = m0 + wm + i * 16 + g * 4;
#pragma unroll
                for (int r = 0; r < 4; r++) {
                    float v = acc[i][j][r] + bv_;
                    if (act) v = (v > 0.f) ? (v + 1.f) : expf(v);
                    C[(size_t)(rowb + r) * N + col] = v;
                }
            }
        }
    }
}

// ---------------------------------------------------------------------------
// Per-chunk Sᵀ_ext[e][d] = Σ_t V_ext[t][e]·K[t][d] via MFMA, e∈0..64 (row 64 = z).
// grid = B*H*NC. Output bf16 linear, 5120 ushorts/block.
// ---------------------------------------------------------------------------
__global__ __launch_bounds__(256) void chunk_kv_mfma(
    const ushort* __restrict__ qkv, ushort* __restrict__ S)
{
    __shared__ __align__(16) ushort sm[9216];   // KT 64x64 @0, VT 80x64 @4096
    int tid = threadIdx.x, lane = tid & 63, wave = tid >> 6;
    int blk = blockIdx.x;
    int c = blk & (NC - 1);
    int bh = blk >> 5;
    int b = bh >> 4, h = bh & 15;
    size_t rowbase = (size_t)(b * TT + c * CC) * QS + h * DH;

    int rrow = tid >> 4, rc4 = (tid & 15) * 4;
#pragma unroll
    for (int r = 0; r < 4; r++) {
        int row = rrow + r * 16;
        ushort4 k4 = *(const ushort4*)&qkv[rowbase + (size_t)row * QS + 1024 + rc4];
        ushort4 v4 = *(const ushort4*)&qkv[rowbase + (size_t)row * QS + 2048 + rc4];
#pragma unroll
        for (int j = 0; j < 4; j++) {
            int d = rc4 + j;
            int pos = (row >> 3) ^ (d & 7);
            sm[0    + d * 64 + pos * 8 + (row & 7)] = ((const ushort*)&k4)[j];
            sm[4096 + d * 64 + pos * 8 + (row & 7)] = ((const ushort*)&v4)[j];
        }
    }
    if (tid < 16) {   // ones row e=64 of VT (swizzle-invariant: constant row)
        ushort4 one4 = make_ushort4(0x3F80, 0x3F80, 0x3F80, 0x3F80);
        *(ushort4*)&sm[4096 + 64 * 64 + tid * 4] = one4;
    }
    __syncthreads();

    int fr = lane & 15, g = lane >> 4;
    short8 bk_[2];
#pragma unroll
    for (int kt = 0; kt < 2; kt++) {
        int row = wave * 16 + fr;
        int kg = kt * 4 + g;
        bk_[kt] = *(const short8*)&sm[0 + row * 64 + (kg ^ (row & 7)) * 8];
    }
    f32x4 acc[5];
#pragma unroll
    for (int it = 0; it < 5; it++) acc[it] = (f32x4){0.f, 0.f, 0.f, 0.f};
#pragma unroll
    for (int it = 0; it < 5; it++) {
        int arow = it * 16 + fr;
#pragma unroll
        for (int kt = 0; kt < 2; kt++) {
            int kg = kt * 4 + g;
            short8 av = *(const short8*)&sm[4096 + arow * 64 + (kg ^ (arow & 7)) * 8];
            acc[it] = __builtin_amdgcn_mfma_f32_16x16x32_bf16(av, bk_[kt], acc[it], 0, 0, 0);
        }
    }
    size_t sb = (size_t)blk * 5120;
#pragma unroll
    for (int it = 0; it < 4; it++)
#pragma unroll
        for (int r = 0; r < 4; r++) {
            int e = it * 16 + g * 4 + r;
            S[sb + e * 64 + wave * 16 + fr] = f2bf(acc[it][r]);
        }
    if (g == 0) S[sb + 64 * 64 + wave * 16 + fr] = f2bf(acc[4][0]);   // z row
}

// ---------------------------------------------------------------------------
// Exclusive prefix over chunks of bf16 Sᵀ_ext (fp32 accumulate); emits bf16
// pre-swizzled SpT (80 rows, rows 65..79 zero). grid = B*H*20 blocks.
// ---------------------------------------------------------------------------
__global__ __launch_bounds__(256) void prefix_scan(
    const ushort* __restrict__ S, ushort* __restrict__ SpT)
{
    int bh = blockIdx.x / 20;
    int seg = blockIdx.x % 20;
    int idx = seg * 256 + threadIdx.x;   // 0..5119
    int e = idx >> 6, d = idx & 63;
    size_t base = (size_t)bh * NC * 5120;
    int pos = (d >> 3) ^ (e & 7);
    size_t woff = (size_t)e * 64 + pos * 8 + (d & 7);
    if (e <= 64) {
        float run = 0.f;
        for (int c = 0; c < NC; c++) {
            size_t boff = base + (size_t)c * 5120;
            float t = bf2f(S[boff + idx]);
            SpT[boff + woff] = f2bf(run);
            run += t;
        }
    } else {
        for (int c = 0; c < NC; c++)
            SpT[base + (size_t)c * 5120 + woff] = 0;
    }
}

// ---------------------------------------------------------------------------
// MFMA chunk attention. Per block (b,h,c):
//   A = Q·Kᵀ ; P = causal-mask(A) (bf16, LDS)
//   O = Q·Sp_ext + P·V_ext   (col 64 = denominator: q·zp + rowsum P)
//   out[t][e] = O[t][e] / max(O[t][64], eps)   -> bf16
// ---------------------------------------------------------------------------
__global__ __launch_bounds__(256) void attn_mfma(
    const ushort* __restrict__ qkv, const ushort* __restrict__ SpT,
    ushort* __restrict__ ob)
{
    __shared__ __align__(16) ushort sm[18432];
    const int LQ = 0, LK = 4096, LSP = 8192, LVT = 13312;
    int tid = threadIdx.x, lane = tid & 63, wave = tid >> 6;
    int blk = blockIdx.x;
    int c = blk & (NC - 1);
    int bh = blk >> 5;
    int b = bh >> 4, h = bh & 15;
    size_t rowbase = (size_t)(b * TT + c * CC) * QS + h * DH;

    // stage Q,K via async16 with global-side swizzle
#pragma unroll
    for (int r = 0; r < 2; r++) {
        int slot = (r * 4 + wave) * 64 + lane;
        int row = slot >> 3, p = slot & 7;
        int kg = p ^ (row & 7);
        const ushort* gq = qkv + rowbase + (size_t)row * QS + kg * 8;
        async16(gq, &sm[LQ + slot * 8]);
        async16(gq + 1024, &sm[LK + slot * 8]);
    }
    // stage SpT (pre-swizzled in global): flat copy, 640 slots
    {
        size_t spbase = (size_t)blk * 5120;
        int slot = wave * 64 + lane;
        async16(SpT + spbase + slot * 8, &sm[LSP + slot * 8]);
        async16(SpT + spbase + (slot + 256) * 8, &sm[LSP + (slot + 256) * 8]);
        if (wave < 2) {
            int s2 = 512 + wave * 64 + lane;
            async16(SpT + spbase + s2 * 8, &sm[LSP + s2 * 8]);
        }
    }
    // stage V transposed (scatter)
    {
        int rrow = tid >> 4, rc4 = (tid & 15) * 4;
#pragma unroll
        for (int r = 0; r < 4; r++) {
            int row = rrow + r * 16;
            ushort4 v4 = *(const ushort4*)&qkv[rowbase + (size_t)row * QS + 2048 + rc4];
#pragma unroll
            for (int j = 0; j < 4; j++) {
                int e = rc4 + j;
                int pos = (row >> 3) ^ (e & 7);
                sm[LVT + e * 64 + pos * 8 + (row & 7)] = ((const ushort*)&v4)[j];
            }
        }
        if (tid < 16) {   // ones row e=64
            ushort4 one4 = make_ushort4(0x3F80, 0x3F80, 0x3F80, 0x3F80);
            *(ushort4*)&sm[LVT + 64 * 64 + tid * 4] = one4;
        }
    }
    __syncthreads();

    int fr = lane & 15, g = lane >> 4;
    int mrow = wave * 16 + fr;

    short8 aq[2];
#pragma unroll
    for (int kt = 0; kt < 2; kt++) {
        int kg = kt * 4 + g;
        aq[kt] = *(const short8*)&sm[LQ + mrow * 64 + (kg ^ (mrow & 7)) * 8];
    }

    // Step A: A = Q·Kᵀ
    f32x4 accA[4];
#pragma unroll
    for (int jt = 0; jt < 4; jt++) accA[jt] = (f32x4){0.f, 0.f, 0.f, 0.f};
#pragma unroll
    for (int jt = 0; jt < 4; jt++) {
        int nrow = jt * 16 + fr;
#pragma unroll
        for (int kt = 0; kt < 2; kt++) {
            int kg = kt * 4 + g;
            short8 bk_ = *(const short8*)&sm[LK + nrow * 64 + (kg ^ (nrow & 7)) * 8];
            accA[jt] = __builtin_amdgcn_mfma_f32_16x16x32_bf16(aq[kt], bk_, accA[jt], 0, 0, 0);
        }
    }
    __syncthreads();

    // mask -> P (bf16) into LK region
#pragma unroll
    for (int jt = 0; jt < 4; jt++) {
        int s = jt * 16 + fr;
#pragma unroll
        for (int r = 0; r < 4; r++) {
            int t = wave * 16 + g * 4 + r;
            float pv = (s <= t) ? accA[jt][r] : 0.f;
            int pos = (s >> 3) ^ (t & 7);
            sm[LK + t * 64 + pos * 8 + (s & 7)] = f2bf(pv);
        }
    }

    // Step B: O += Q·Sp_ext
    f32x4 acc[5];
#pragma unroll
    for (int jt = 0; jt < 5; jt++) acc[jt] = (f32x4){0.f, 0.f, 0.f, 0.f};
#pragma unroll
    for (int jt = 0; jt < 5; jt++) {
        int nrow = jt * 16 + fr;
#pragma unroll
        for (int kt = 0; kt < 2; kt++) {
            int kg = kt * 4 + g;
            short8 bsp = *(const short8*)&sm[LSP + nrow * 64 + (kg ^ (nrow & 7)) * 8];
            acc[jt] = __builtin_amdgcn_mfma_f32_16x16x32_bf16(aq[kt], bsp, acc[jt], 0, 0, 0);
        }
    }
    __syncthreads();

    // Step C: O += P·V_ext
    short8 ap[2];
#pragma unroll
    for (int kt = 0; kt < 2; kt++) {
        int kg = kt * 4 + g;
        ap[kt] = *(const short8*)&sm[LK + mrow * 64 + (kg ^ (mrow & 7)) * 8];
    }
#pragma unroll
    for (int jt = 0; jt < 5; jt++) {
        int nrow = jt * 16 + fr;
#pragma unroll
        for (int kt = 0; kt < 2; kt++) {
            int kg = kt * 4 + g;
            short8 bvt = *(const short8*)&sm[LVT + nrow * 64 + (kg ^ (nrow & 7)) * 8];
            acc[jt] = __builtin_amdgcn_mfma_f32_16x16x32_bf16(ap[kt], bvt, acc[jt], 0, 0, 0);
        }
    }

    // denominator broadcast
    int srcl = g * 16;
    float rdi[4];
#pragma unroll
    for (int r = 0; r < 4; r++) {
        float den = __shfl(acc[4][r], srcl, 64);
        rdi[r] = 1.f / fmaxf(den, EPSV);
    }
    // write O bf16 to stage (stride 72, overlays LSP region)
#pragma unroll
    for (int jt = 0; jt < 4; jt++) {
        int e = jt * 16 + fr;
#pragma unroll
        for (int r = 0; r < 4; r++) {
            int t = wave * 16 + g * 4 + r;
            sm[LSP + t * 72 + e] = f2bf(acc[jt][r] * rdi[r]);
        }
    }
    __syncthreads();

    // coalesced 16B global stores
#pragma unroll
    for (int it = 0; it < 2; it++) {
        int slot = it * 256 + tid;
        int row = slot >> 3, ch = slot & 7;
        ushort4 lo = *(const ushort4*)&sm[LSP + row * 72 + ch * 8];
        ushort4 hi = *(const ushort4*)&sm[LSP + row * 72 + ch * 8 + 4];
        ushort pk8[8] = {lo.x, lo.y, lo.z, lo.w, hi.x, hi.y, hi.z, hi.w};
        *(uint4*)&ob[(size_t)(b * TT + c * CC + row) * DD + h * DH + ch * 8] = *(uint4*)pk8;
    }
}

// ---------------------------------------------------------------------------
extern "C" void kernel_launch(void* const* d_in, const int* in_sizes, int n_in,
                              void* d_out, int out_size, void* d_ws, size_t ws_size,
                              hipStream_t stream) {
    const float* x  = (const float*)d_in[0];
    const float* Wq = (const float*)d_in[1];
    const float* bq = (const float*)d_in[2];
    const float* Wk = (const float*)d_in[3];
    const float* bk = (const float*)d_in[4];
    const float* Wv = (const float*)d_in[5];
    const float* bv = (const float*)d_in[6];
    const float* Wo = (const float*)d_in[7];
    const float* bo = (const float*)d_in[8];
    float* out = (float*)d_out;

    char* ws = (char*)d_ws;
    ushort* xb    = (ushort*)(ws + 0);          //  8388608 B
    ushort* Wqkvb = (ushort*)(ws + 8388608);    //  6291456 B
    ushort* Wob   = (ushort*)(ws + 14680064);   //  2097152 B
    float*  biasq = (float*)(ws + 16777216);    //    12288 B
    ushort* qkvb  = (ushort*)(ws + 16789504);   // 25165824 B (4096x3072 bf16)
    ushort* Sb    = (ushort*)(ws + 41955328);   // 10485760 B (1024x5120 bf16)
    ushort* SpTb  = (ushort*)(ws + 52441088);   // 10485760 B
    ushort* attnb = (ushort*)(ws + 0);          // reuse xb region

    convert_pack<<<4096, 256, 0, stream>>>(x, Wq, Wk, Wv, Wo, bq, bk, bv,
                                           xb, Wqkvb, Wob, biasq);
    gemm_mfma<128, 128, true><<<dim3(3072 / 128, BT / 128), 256, 0, stream>>>(
        xb, Wqkvb, biasq, qkvb, BT, 3072, DD, 2048);
    chunk_kv_mfma<<<BB * HH * NC, 256, 0, stream>>>(qkvb, Sb);
    prefix_scan<<<BB * HH * 20, 256, 0, stream>>>(Sb, SpTb);
    attn_mfma<<<BB * HH * NC, 256, 0, stream>>>(qkvb, SpTb, attnb);
    gemm_mfma<64, 128, false><<<dim3(DD / 128, BT / 64), 256, 0, stream>>>(
        attnb, Wob, bo, out, BT, DD, DD, 0);
}